// Round 3
// baseline (498.535 us; speedup 1.0000x reference)
//
#include <hip/hip_runtime.h>

// ProtoNet: out[q][n] = -|| (xq[q]@W + b) - proto[n] ||^2
// v3: ONE persistent kernel (512 blocks x 256 thr, all co-resident) with a
// software grid barrier between phases — removes ~5 kernel-boundary overheads.
//   phase0: zero out; transpose W -> Wt bf16 [512][2048]; bin ys by class
//   phase1: csum[64][2048] class sums (f32)
//   phase2: proto partials [8][64][512] (W read once, no atomics)
//   phase3: proto finalize -> proto_bf + per-128-slice pnorm_part[4][64]
//   phase4: z = xq@W + b (m97-structure 128x128 GEMM) + fused distance
//           epilogue: out += 2*z@proto_s^T - |z_s|^2 - |p_s|^2 (atomicAdd)

typedef __attribute__((ext_vector_type(8))) short short8;
typedef __attribute__((ext_vector_type(4))) float floatx4;

#define S_ROWS 1024
#define F_DIM  2048
#define D_DIM  512
#define NWAY   64
#define Q_ROWS 16384
#define NBLK   512
#define ZS_LD  136

static __device__ __forceinline__ unsigned short f2bf(float f) {
  unsigned int u = __float_as_uint(f);
  u += 0x7FFF + ((u >> 16) & 1);   // RNE
  return (unsigned short)(u >> 16);
}
static __device__ __forceinline__ float bf2f(unsigned short s) {
  return __uint_as_float(((unsigned int)s) << 16);
}
// pack two floats -> two bf16 (round-half-up; ties-only deviation from RNE)
static __device__ __forceinline__ unsigned int pack_bf2(float x, float y) {
  unsigned int ux = __float_as_uint(x) + 0x8000u;
  unsigned int uy = __float_as_uint(y) + 0x8000u;
  return __builtin_amdgcn_perm(uy, ux, 0x07060302u);  // hi16(uy)<<16 | hi16(ux)
}
// async global->LDS, 16B per lane. LDS dest = wave-uniform base + lane*16.
static __device__ __forceinline__ void load_lds16(const unsigned short* g, unsigned short* l) {
  __builtin_amdgcn_global_load_lds((const __attribute__((address_space(1))) unsigned int*)g,
                                   (__attribute__((address_space(3))) unsigned int*)l,
                                   16, 0, 0);
}

// software grid barrier (sense-reversal on generation counter).
// Safe: all NBLK blocks are co-resident (LDS 35.6KB -> 4 blk/CU,
// launch_bounds(256,2) -> VGPR<=256 -> >=2 blk/CU -> capacity >= 512).
static __device__ __forceinline__ void grid_sync(int* bcnt, int* bgen) {
  __syncthreads();
  if (threadIdx.x == 0) {
    __threadfence();                       // release: make this block's stores visible
    int g = atomicAdd(bgen, 0);            // read current generation
    if (atomicAdd(bcnt, 1) == NBLK - 1) {
      atomicExch(bcnt, 0);
      __threadfence();
      atomicAdd(bgen, 1);
    } else {
      while (atomicAdd(bgen, 0) == g) __builtin_amdgcn_s_sleep(8);
    }
    __threadfence();                       // acquire: invalidate stale cached data
  }
  __syncthreads();
}

__global__ __launch_bounds__(256, 2) void mega(
    const float* __restrict__ xs, const int* __restrict__ ys,
    const float* __restrict__ xq, const float* __restrict__ W,
    const float* __restrict__ b, float* __restrict__ out,
    unsigned short* __restrict__ Wt, float* __restrict__ csum,
    float* __restrict__ proto_part, unsigned short* __restrict__ proto_bf,
    float* __restrict__ pnorm_part, int* __restrict__ order,
    int* __restrict__ starts, int* __restrict__ bar) {
  __shared__ __align__(16) char smem[35584];
  int bx = blockIdx.x;
  int tid = threadIdx.x;
  int* bcnt = bar;
  int* bgen = bar + 1;

  // ================= phase 0: zero out, transpose W, bin ys =================
  {
    float4 zz = {0.f, 0.f, 0.f, 0.f};
    float* dst = out + (size_t)bx * 2048 + tid * 8;   // 512*2048 = 16384*64
    *(float4*)dst = zz;
    *(float4*)(dst + 4) = zz;
  }
  if (bx < 256) {
    unsigned short(*t)[65] = (unsigned short(*)[65])smem;
    int f0 = (bx >> 3) << 6;   // 32 f-tiles
    int d0 = (bx & 7) << 6;    // 8 d-tiles
    for (int j = 0; j < 16; j++) {
      int lin = j * 256 + tid;
      int fl = lin >> 6, dl = lin & 63;
      t[fl][dl] = f2bf(W[(size_t)(f0 + fl) * D_DIM + d0 + dl]);
    }
    __syncthreads();
    for (int j = 0; j < 16; j++) {
      int lin = j * 256 + tid;
      int dl = lin >> 6, fl = lin & 63;
      Wt[(size_t)(d0 + dl) * F_DIM + f0 + fl] = t[fl][dl];
    }
  } else if (bx == 256) {
    int* cnt = (int*)smem;             // 64 ints
    int* st = (int*)(smem + 256);      // 65 ints
    int* wp = (int*)(smem + 520);      // 64 ints
    if (tid < NWAY) cnt[tid] = 0;
    __syncthreads();
    for (int j = tid; j < S_ROWS; j += 256) atomicAdd(&cnt[ys[j]], 1);
    __syncthreads();
    if (tid == 0) {
      int a = 0;
      for (int c = 0; c < NWAY; c++) { st[c] = a; wp[c] = a; a += cnt[c]; }
      st[NWAY] = a;
    }
    __syncthreads();
    for (int j = tid; j < S_ROWS; j += 256) {
      int c = ys[j];
      int p = atomicAdd(&wp[c], 1);
      order[p] = j;
    }
    if (tid < NWAY + 1) starts[tid] = st[tid];
  }
  grid_sync(bcnt, bgen);

  // ================= phase 1: class sums (blocks 0..127) =================
  if (bx < 128) {
    int* lord = (int*)smem;
    int c = bx >> 1;
    int s = starts[c], e = starts[c + 1];
    int len = e - s;
    for (int j = tid; j < len; j += 256) lord[j] = order[s + j];
    __syncthreads();
    int f0 = (bx & 1) * 1024 + tid * 4;
    float4 a = {0.f, 0.f, 0.f, 0.f};
    for (int i = 0; i < len; i++) {
      float4 v = *(const float4*)&xs[(size_t)lord[i] * F_DIM + f0];
      a.x += v.x; a.y += v.y; a.z += v.z; a.w += v.w;
    }
    *(float4*)&csum[(size_t)c * F_DIM + f0] = a;
  }
  grid_sync(bcnt, bgen);

  // ================= phase 2: proto partials (blocks 0..63) =================
  if (bx < 64) {
    float* csl = (float*)smem;                 // 64*65 f32
    float* wch = (float*)(smem + 16640);       // 64*64 f32
    int fg = bx >> 3, dc = bx & 7;
    int d0 = dc * 64;
    int c = tid >> 2, dq = (tid & 3) * 16;
    floatx4 a0 = {0.f, 0.f, 0.f, 0.f}, a1 = a0, a2 = a0, a3 = a0;
    for (int fsub = 0; fsub < 4; fsub++) {
      int f0 = (fg * 4 + fsub) * 64;
      __syncthreads();
      for (int idx = tid; idx < 4096; idx += 256) {
        int r = idx >> 6, q = idx & 63;
        csl[r * 65 + q] = csum[(size_t)r * F_DIM + f0 + q];
        wch[idx] = W[(size_t)(f0 + r) * D_DIM + d0 + q];
      }
      __syncthreads();
#pragma unroll 4
      for (int f = 0; f < 64; f++) {
        float sv = csl[c * 65 + f];
        const floatx4* wr = (const floatx4*)&wch[f * 64 + dq];
        floatx4 w0 = wr[0], w1 = wr[1], w2 = wr[2], w3 = wr[3];
        a0 += sv * w0; a1 += sv * w1; a2 += sv * w2; a3 += sv * w3;
      }
    }
    float* dst = &proto_part[((size_t)fg * NWAY + c) * D_DIM + d0 + dq];
    *(floatx4*)&dst[0] = a0;
    *(floatx4*)&dst[4] = a1;
    *(floatx4*)&dst[8] = a2;
    *(floatx4*)&dst[12] = a3;
  }
  grid_sync(bcnt, bgen);

  // ================= phase 3: proto finalize + slice pnorm (blocks 0..63) ===
  if (bx < 64) {
    float* red = (float*)smem;
    int n = bx;
    float cntv = (float)(starts[n + 1] - starts[n]);
    float inv = 1.f / fmaxf(cntv, 1.f);
#pragma unroll
    for (int h = 0; h < 2; h++) {
      int d = h * 256 + tid;
      float raw = 0.f;
#pragma unroll
      for (int p = 0; p < 8; p++)
        raw += proto_part[((size_t)p * NWAY + n) * D_DIM + d];
      float pv = (raw + cntv * b[d]) * inv;   // cnt==0 -> 0, matches ref
      unsigned short hh = f2bf(pv);
      proto_bf[(size_t)n * D_DIM + d] = hh;
      float q = bf2f(hh);
      __syncthreads();
      red[tid] = q * q;
      __syncthreads();
      for (int s = 64; s > 0; s >>= 1) {
        if ((tid & 127) < s) red[tid] += red[tid + s];
        __syncthreads();
      }
      if (tid == 0) pnorm_part[(h * 2 + 0) * 64 + n] = red[0];
      if (tid == 128) pnorm_part[(h * 2 + 1) * 64 + n] = red[128];
    }
  }
  grid_sync(bcnt, bgen);

  // ================= phase 4: z-GEMM + fused distance epilogue ==============
  {
    unsigned short* lA = (unsigned short*)smem;            // 128 x 64 halfs
    unsigned short* lB = (unsigned short*)(smem + 16384);  // 128 x 64 halfs
    unsigned short* zs = (unsigned short*)smem;            // 128 x ZS_LD (epilogue)
    float* qnf = (float*)(smem + 34816);                   // 128
    float* pnl = (float*)(smem + 35328);                   // 64

    // XCD swizzle (512 % 8 == 0, bijective): 4 n-slices of an m-tile are
    // dispatch-neighbors on the same XCD -> L2 reuse of xq.
    int xcd = bx & 7;
    int wg = xcd * 64 + (bx >> 3);
    int mt = wg >> 2;                 // 0..127
    int slice = wg & 3;
    int n0 = slice * 128;

    int wave = tid >> 6, lane = tid & 63;
    int wr = wave >> 1, wc = wave & 1;
    int lrow = lane & 15, lquad = lane >> 4;

    const float* Ab = xq + (size_t)mt * 128 * F_DIM;

    floatx4 acc[4][4];
#pragma unroll
    for (int i = 0; i < 4; i++)
#pragma unroll
      for (int j = 0; j < 4; j++) acc[i][j] = (floatx4){0.f, 0.f, 0.f, 0.f};

    int sr = tid >> 3, skq = tid & 7;
    const float* ag = Ab + (size_t)sr * F_DIM + skq * 8;
    const unsigned short* bg = Wt + (size_t)(n0 + sr) * F_DIM + skq * 8;

    for (int k0 = 0; k0 < F_DIM; k0 += 64) {
#pragma unroll
      for (int i = 0; i < 4; i++)
        load_lds16(bg + (size_t)i * 32 * F_DIM + k0, &lB[(i * 256 + wave * 64) * 8]);
#pragma unroll
      for (int p = 0; p < 4; p++) {
        const float* gp = ag + (size_t)p * 32 * F_DIM + k0;
        float4 v0 = *(const float4*)gp;
        float4 v1 = *(const float4*)(gp + 4);
        uint4 w;
        w.x = pack_bf2(v0.x, v0.y); w.y = pack_bf2(v0.z, v0.w);
        w.z = pack_bf2(v1.x, v1.y); w.w = pack_bf2(v1.z, v1.w);
        *(uint4*)&lA[(p * 256 + tid) * 8] = w;
      }
      __syncthreads();
#pragma unroll
      for (int s = 0; s < 2; s++) {
        short8 af[4], bfr[4];
#pragma unroll
        for (int i = 0; i < 4; i++)
          af[i] = *(const short8*)&lA[(wr * 64 + i * 16 + lrow) * 64 + s * 32 + lquad * 8];
#pragma unroll
        for (int j = 0; j < 4; j++)
          bfr[j] = *(const short8*)&lB[(wc * 64 + j * 16 + lrow) * 64 + s * 32 + lquad * 8];
#pragma unroll
        for (int i = 0; i < 4; i++)
#pragma unroll
          for (int j = 0; j < 4; j++)
            acc[i][j] = __builtin_amdgcn_mfma_f32_16x16x32_bf16(af[i], bfr[j], acc[i][j], 0, 0, 0);
      }
      __syncthreads();
    }

    // epilogue A: init qn accumulator + load per-slice proto norms
    if (tid < 128) qnf[tid] = 0.f;
    if (tid < 64) pnl[tid] = pnorm_part[slice * 64 + tid];
    __syncthreads();

    // epilogue B: z -> LDS bf16 (128 x 128) + per-row slice norms
#pragma unroll
    for (int i = 0; i < 4; i++) {
      float rn[4] = {0.f, 0.f, 0.f, 0.f};
#pragma unroll
      for (int j = 0; j < 4; j++) {
        int col = wc * 64 + j * 16 + lrow;          // local d (0..127)
        float bb = b[n0 + col];
#pragma unroll
        for (int r = 0; r < 4; r++) {
          int row = wr * 64 + i * 16 + lquad * 4 + r;  // local q (0..127)
          float v = acc[i][j][r] + bb;
          unsigned short h = f2bf(v);
          zs[row * ZS_LD + col] = h;
          float vq = bf2f(h);
          rn[r] += vq * vq;
        }
      }
#pragma unroll
      for (int r = 0; r < 4; r++) {
        float s2 = rn[r];
        s2 += __shfl_xor(s2, 1, 16);
        s2 += __shfl_xor(s2, 2, 16);
        s2 += __shfl_xor(s2, 4, 16);
        s2 += __shfl_xor(s2, 8, 16);
        if (lrow == 0) atomicAdd(&qnf[wr * 64 + i * 16 + lquad * 4 + r], s2);
      }
    }
    __syncthreads();

    // epilogue C: S = zs(128x128) @ proto_slice(64x128)^T; wave -> 32 q-rows.
    // proto B-frags straight from global (proto_bf is 64KB, L2-hot).
    floatx4 acc2[2][4];
#pragma unroll
    for (int i = 0; i < 2; i++)
#pragma unroll
      for (int j = 0; j < 4; j++) acc2[i][j] = (floatx4){0.f, 0.f, 0.f, 0.f};

#pragma unroll
    for (int ks = 0; ks < 4; ks++) {
      short8 af2[2], bp[4];
#pragma unroll
      for (int i = 0; i < 2; i++)
        af2[i] = *(const short8*)&zs[(wave * 32 + i * 16 + lrow) * ZS_LD + ks * 32 + lquad * 8];
#pragma unroll
      for (int j = 0; j < 4; j++)
        bp[j] = *(const short8*)&proto_bf[(size_t)(j * 16 + lrow) * D_DIM + n0 + ks * 32 + lquad * 8];
#pragma unroll
      for (int i = 0; i < 2; i++)
#pragma unroll
        for (int j = 0; j < 4; j++)
          acc2[i][j] = __builtin_amdgcn_mfma_f32_16x16x32_bf16(af2[i], bp[j], acc2[i][j], 0, 0, 0);
    }

    // epilogue D: out += 2S - qn_slice - pn_slice
    size_t qbase = (size_t)mt * 128;
#pragma unroll
    for (int i = 0; i < 2; i++) {
#pragma unroll
      for (int j = 0; j < 4; j++) {
        int c = j * 16 + lrow;
        float pn = pnl[c];
#pragma unroll
        for (int r = 0; r < 4; r++) {
          int ql = wave * 32 + i * 16 + lquad * 4 + r;
          float val = 2.f * acc2[i][j][r] - qnf[ql] - pn;
          atomicAdd(&out[(qbase + ql) * NWAY + c], val);
        }
      }
    }
  }
}

extern "C" void kernel_launch(void* const* d_in, const int* in_sizes, int n_in,
                              void* d_out, int out_size, void* d_ws, size_t ws_size,
                              hipStream_t stream) {
  const float* xs = (const float*)d_in[0];
  const int* ys = (const int*)d_in[1];
  const float* xq = (const float*)d_in[2];
  const float* W = (const float*)d_in[3];
  const float* b = (const float*)d_in[4];
  float* out = (float*)d_out;
  char* ws = (char*)d_ws;

  size_t off = 0;
  auto take = [&](size_t bytes) -> char* {
    char* r = ws + off;
    off += (bytes + 255) & ~(size_t)255;
    return r;
  };
  unsigned short* Wt = (unsigned short*)take((size_t)D_DIM * F_DIM * 2);       // 2 MB
  float* csum = (float*)take((size_t)NWAY * F_DIM * 4);                        // 512 KB
  float* proto_part = (float*)take((size_t)8 * NWAY * D_DIM * 4);              // 1 MB
  unsigned short* proto_bf = (unsigned short*)take((size_t)NWAY * D_DIM * 2);  // 64 KB
  float* pnorm_part = (float*)take(4 * NWAY * 4);
  int* order = (int*)take(S_ROWS * 4);
  int* starts = (int*)take((NWAY + 1) * 4);
  int* bar = (int*)take(256);

  // Workspace guard: fail cleanly rather than corrupt device memory.
  if (off > ws_size) return;

  hipMemsetAsync(bar, 0, 8, stream);
  mega<<<NBLK, 256, 0, stream>>>(xs, ys, xq, W, b, out, Wt, csum, proto_part,
                                 proto_bf, pnorm_part, order, starts, bar);
}

// Round 4
// 326.358 us; speedup vs baseline: 1.5276x; 1.5276x over previous
//
#include <hip/hip_runtime.h>

// ProtoNet: out[q][n] = -|| (xq[q]@W + b) - proto[n] ||^2
// v4: 4 launches (grid barriers removed — round-3 showed contended-atomic
// barriers cost ~270us). k3 is a double-buffered, issue-early/write-late
// pipelined GEMM (1 barrier per K-step) + fused distance epilogue.
//   k_prep : transpose W -> Wt bf16; zero out + pnorm_part; bin ys
//   k1_csum: per-class support sums (f32)            -> csum [64][2048]
//   k2_full: proto = csum@W/cnt + b in one shot      -> proto_bf + pnorm_part
//   k3_fused: z = xq@W + b (128x128 tile, dbuf pipeline) + per-128-slice
//             distance epilogue, atomicAdd into pre-zeroed out.

typedef __attribute__((ext_vector_type(8))) short short8;
typedef __attribute__((ext_vector_type(4))) float floatx4;

#define S_ROWS 1024
#define F_DIM  2048
#define D_DIM  512
#define NWAY   64
#define Q_ROWS 16384
#define ZS_LD  136

static __device__ __forceinline__ unsigned short f2bf(float f) {
  unsigned int u = __float_as_uint(f);
  u += 0x7FFF + ((u >> 16) & 1);   // RNE
  return (unsigned short)(u >> 16);
}
static __device__ __forceinline__ float bf2f(unsigned short s) {
  return __uint_as_float(((unsigned int)s) << 16);
}
// pack two floats -> two bf16 (round-half-up; ties-only deviation from RNE)
static __device__ __forceinline__ unsigned int pack_bf2(float x, float y) {
  unsigned int ux = __float_as_uint(x) + 0x8000u;
  unsigned int uy = __float_as_uint(y) + 0x8000u;
  return __builtin_amdgcn_perm(uy, ux, 0x07060302u);  // hi16(uy)<<16 | hi16(ux)
}
// async global->LDS, 16B per lane. LDS dest = wave-uniform base + lane*16.
static __device__ __forceinline__ void load_lds16(const unsigned short* g, unsigned short* l) {
  __builtin_amdgcn_global_load_lds((const __attribute__((address_space(1))) unsigned int*)g,
                                   (__attribute__((address_space(3))) unsigned int*)l,
                                   16, 0, 0);
}

// ---- k_prep: blocks 0..255 transpose W + zero their slice of out;
//      block 256 bins support ids by class + zeroes pnorm_part ----
__global__ __launch_bounds__(256) void k_prep(const float* __restrict__ W,
                                              unsigned short* __restrict__ Wt,
                                              float* __restrict__ outz,
                                              float* __restrict__ pnorm_part,
                                              const int* __restrict__ ys,
                                              int* __restrict__ order,
                                              int* __restrict__ starts,
                                              float* __restrict__ counts) {
  __shared__ unsigned short t[64][65];
  __shared__ int cnt[NWAY];
  __shared__ int st[NWAY + 1];
  __shared__ int wp[NWAY];
  int bx = blockIdx.x;
  int tid = threadIdx.x;
  if (bx < 256) {
    // zero this block's slice of out (16384*64 f32 total)
    float4 zz = {0.f, 0.f, 0.f, 0.f};
#pragma unroll
    for (int p = 0; p < 4; p++)
      *(float4*)&outz[(size_t)bx * 4096 + p * 1024 + tid * 4] = zz;
    int f0 = (bx >> 3) << 6;   // 32 f-tiles
    int d0 = (bx & 7) << 6;    // 8 d-tiles
    for (int j = 0; j < 16; j++) {
      int lin = j * 256 + tid;
      int fl = lin >> 6, dl = lin & 63;
      t[fl][dl] = f2bf(W[(size_t)(f0 + fl) * D_DIM + d0 + dl]);
    }
    __syncthreads();
    for (int j = 0; j < 16; j++) {
      int lin = j * 256 + tid;
      int dl = lin >> 6, fl = lin & 63;
      Wt[(size_t)(d0 + dl) * F_DIM + f0 + fl] = t[fl][dl];
    }
  } else {
    pnorm_part[tid] = 0.f;   // 256 entries = [4 slices][64 classes]
    if (tid < NWAY) cnt[tid] = 0;
    __syncthreads();
    for (int j = tid; j < S_ROWS; j += 256) atomicAdd(&cnt[ys[j]], 1);
    __syncthreads();
    if (tid == 0) {
      int a = 0;
      for (int c = 0; c < NWAY; c++) { st[c] = a; wp[c] = a; a += cnt[c]; }
      st[NWAY] = a;
    }
    __syncthreads();
    for (int j = tid; j < S_ROWS; j += 256) {
      int c = ys[j];
      int p = atomicAdd(&wp[c], 1);
      order[p] = j;
    }
    if (tid < NWAY) counts[tid] = (float)cnt[tid];
    if (tid < NWAY + 1) starts[tid] = st[tid];
  }
}

// ---- K1: class sums. grid = 64 classes x 2 f-tiles; float4 per thread ----
__global__ __launch_bounds__(256) void k1_csum(const float* __restrict__ xs,
                                               const int* __restrict__ order,
                                               const int* __restrict__ starts,
                                               float* __restrict__ csum) {
  __shared__ int lord[S_ROWS];
  int c = blockIdx.x >> 1;
  int tid = threadIdx.x;
  int s = starts[c], e = starts[c + 1];
  int len = e - s;
  for (int j = tid; j < len; j += 256) lord[j] = order[s + j];
  __syncthreads();
  int f0 = (blockIdx.x & 1) * 1024 + tid * 4;
  float4 a = {0.f, 0.f, 0.f, 0.f};
  for (int i = 0; i < len; i++) {
    float4 v = *(const float4*)&xs[(size_t)lord[i] * F_DIM + f0];
    a.x += v.x; a.y += v.y; a.z += v.z; a.w += v.w;
  }
  *(float4*)&csum[(size_t)c * F_DIM + f0] = a;
}

// ---- k2_full: proto in one shot. grid = 8 class-groups x 8 d-chunks = 64.
//      Block: 8 classes x 64 d cols, full K=2048 via 32 LDS-staged chunks.
//      Writes proto_bf + atomicAdd per-slice pnorm_part. ----
__global__ __launch_bounds__(256) void k2_full(const float* __restrict__ W,
                                               const float* __restrict__ csum,
                                               const float* __restrict__ b,
                                               const float* __restrict__ counts,
                                               unsigned short* __restrict__ proto_bf,
                                               float* __restrict__ pnorm_part) {
  __shared__ __align__(16) float wch[64 * 64];   // 16 KB
  __shared__ float csl[8 * 64];                  // 2 KB
  int bx = blockIdx.x;
  int cg = bx >> 3, dc = bx & 7;
  int c0 = cg * 8, d0 = dc * 64;
  int tid = threadIdx.x;
  int cl = tid >> 5;          // local class 0..7
  int dl = (tid & 31) * 2;    // local d col pair
  float a0 = 0.f, a1 = 0.f;
  for (int fs = 0; fs < 32; fs++) {
    int f0 = fs * 64;
    __syncthreads();
    for (int idx = tid; idx < 4096; idx += 256) {
      int r = idx >> 6, q = idx & 63;
      wch[idx] = W[(size_t)(f0 + r) * D_DIM + d0 + q];
    }
    for (int idx = tid; idx < 512; idx += 256) {
      int r = idx >> 6, q = idx & 63;
      csl[idx] = csum[(size_t)(c0 + r) * F_DIM + f0 + q];
    }
    __syncthreads();
#pragma unroll 8
    for (int f = 0; f < 64; f++) {
      float s = csl[cl * 64 + f];
      a0 += s * wch[f * 64 + dl];
      a1 += s * wch[f * 64 + dl + 1];
    }
  }
  int c = c0 + cl;
  float cntv = counts[c];
  float inv = 1.f / fmaxf(cntv, 1.f);
  float p0 = (a0 + cntv * b[d0 + dl]) * inv;     // cnt==0 -> 0, matches ref
  float p1 = (a1 + cntv * b[d0 + dl + 1]) * inv;
  unsigned short h0 = f2bf(p0), h1 = f2bf(p1);
  proto_bf[(size_t)c * D_DIM + d0 + dl] = h0;
  proto_bf[(size_t)c * D_DIM + d0 + dl + 1] = h1;
  float q0 = bf2f(h0), q1 = bf2f(h1);
  float s2 = q0 * q0 + q1 * q1;
  s2 += __shfl_xor(s2, 1, 32);
  s2 += __shfl_xor(s2, 2, 32);
  s2 += __shfl_xor(s2, 4, 32);
  s2 += __shfl_xor(s2, 8, 32);
  s2 += __shfl_xor(s2, 16, 32);
  if ((tid & 31) == 0) atomicAdd(&pnorm_part[(dc >> 1) * 64 + c], s2);
}

// ---- k3_fused: pipelined 128x128 GEMM (dbuf, 1 barrier/K-step) + fused
//      distance epilogue. grid = 128 m-tiles x 4 n-slices = 512 blocks. ----
__global__ __launch_bounds__(256) void k3_fused(const float* __restrict__ xq,
                                                const unsigned short* __restrict__ Wt,
                                                const float* __restrict__ b,
                                                const unsigned short* __restrict__ proto_bf,
                                                const float* __restrict__ pnorm_part,
                                                float* __restrict__ out) {
  // LDS: dbuf [2][lA 16K + lB 16K] = 64K; epilogue overlays zs on buf region.
  __shared__ __align__(16) char smem[66304];
  unsigned short* lA0 = (unsigned short*)smem;
  unsigned short* lB0 = (unsigned short*)(smem + 16384);
  unsigned short* lA1 = (unsigned short*)(smem + 32768);
  unsigned short* lB1 = (unsigned short*)(smem + 49152);
  unsigned short* zs = (unsigned short*)smem;      // 128 x ZS_LD halfs (34816 B)
  float* qnf = (float*)(smem + 65536);             // 128
  float* pnl = (float*)(smem + 66048);             // 64

  int tid = threadIdx.x;
  int bx = blockIdx.x;
  // XCD swizzle (512 % 8 == 0, bijective): 4 n-slices of an m-tile are
  // dispatch-neighbors on the same XCD -> L2 reuse of xq.
  int xcd = bx & 7;
  int wg = xcd * 64 + (bx >> 3);
  int mt = wg >> 2;                 // 0..127
  int slice = wg & 3;
  int n0 = slice * 128;

  int wave = tid >> 6, lane = tid & 63;
  int wr = wave >> 1, wc = wave & 1;
  int lrow = lane & 15, lquad = lane >> 4;

  const float* Ab = xq + (size_t)mt * 128 * F_DIM;

  floatx4 acc[4][4];
#pragma unroll
  for (int i = 0; i < 4; i++)
#pragma unroll
    for (int j = 0; j < 4; j++) acc[i][j] = (floatx4){0.f, 0.f, 0.f, 0.f};

  int sr = tid >> 3, skq = tid & 7;
  const float* ag = Ab + (size_t)sr * F_DIM + skq * 8;
  const unsigned short* bg = Wt + (size_t)(n0 + sr) * F_DIM + skq * 8;

  float4 pf[4][2];   // A prefetch registers (32 VGPR)

  auto stageB = [&](unsigned short* lBbuf, int k0) {
#pragma unroll
    for (int i = 0; i < 4; i++)
      load_lds16(bg + (size_t)i * 32 * F_DIM + k0, &lBbuf[(i * 256 + wave * 64) * 8]);
  };
  auto issueA = [&](int k0) {
#pragma unroll
    for (int p = 0; p < 4; p++) {
      const float* gp = ag + (size_t)p * 32 * F_DIM + k0;
      pf[p][0] = *(const float4*)gp;
      pf[p][1] = *(const float4*)(gp + 4);
    }
  };
  auto writeA = [&](unsigned short* lAbuf) {
#pragma unroll
    for (int p = 0; p < 4; p++) {
      uint4 w;
      w.x = pack_bf2(pf[p][0].x, pf[p][0].y);
      w.y = pack_bf2(pf[p][0].z, pf[p][0].w);
      w.z = pack_bf2(pf[p][1].x, pf[p][1].y);
      w.w = pack_bf2(pf[p][1].z, pf[p][1].w);
      *(uint4*)&lAbuf[(p * 256 + tid) * 8] = w;
    }
  };
  auto compute = [&](const unsigned short* lAbuf, const unsigned short* lBbuf) {
#pragma unroll
    for (int s = 0; s < 2; s++) {
      short8 af[4], bfr[4];
#pragma unroll
      for (int i = 0; i < 4; i++)
        af[i] = *(const short8*)&lAbuf[(wr * 64 + i * 16 + lrow) * 64 + s * 32 + lquad * 8];
#pragma unroll
      for (int j = 0; j < 4; j++)
        bfr[j] = *(const short8*)&lBbuf[(wc * 64 + j * 16 + lrow) * 64 + s * 32 + lquad * 8];
#pragma unroll
      for (int i = 0; i < 4; i++)
#pragma unroll
        for (int j = 0; j < 4; j++)
          acc[i][j] = __builtin_amdgcn_mfma_f32_16x16x32_bf16(af[i], bfr[j], acc[i][j], 0, 0, 0);
    }
  };

  // prologue: stage k-step 0 into buf0
  stageB(lB0, 0);
  issueA(0);
  writeA(lA0);
  __syncthreads();

  // pipelined main loop: issue t+1's loads early, consume after t's MFMA.
  for (int t = 0; t < 32; t += 2) {
    {  // step t: compute buf0, stage t+1 -> buf1
      int kn = (t + 1) * 64;
      stageB(lB1, kn);
      issueA(kn);
      compute(lA0, lB0);
      writeA(lA1);
      __syncthreads();
    }
    {  // step t+1: compute buf1, stage t+2 -> buf0
      if (t + 2 < 32) {
        int kn = (t + 2) * 64;
        stageB(lB0, kn);
        issueA(kn);
      }
      compute(lA1, lB1);
      if (t + 2 < 32) writeA(lA0);
      __syncthreads();
    }
  }

  // ---- epilogue A: init qn accumulator + load per-slice proto norms ----
  if (tid < 128) qnf[tid] = 0.f;
  if (tid < 64) pnl[tid] = pnorm_part[slice * 64 + tid];
  __syncthreads();

  // ---- epilogue B: z -> LDS bf16 (128 x 128) + per-row slice norms ----
#pragma unroll
  for (int i = 0; i < 4; i++) {
    float rn[4] = {0.f, 0.f, 0.f, 0.f};
#pragma unroll
    for (int j = 0; j < 4; j++) {
      int col = wc * 64 + j * 16 + lrow;              // local d (0..127)
      float bb = b[n0 + col];
#pragma unroll
      for (int r = 0; r < 4; r++) {
        int row = wr * 64 + i * 16 + lquad * 4 + r;   // local q (0..127)
        float v = acc[i][j][r] + bb;
        unsigned short h = f2bf(v);
        zs[row * ZS_LD + col] = h;
        float vq = bf2f(h);
        rn[r] += vq * vq;
      }
    }
#pragma unroll
    for (int r = 0; r < 4; r++) {
      float s2 = rn[r];
      s2 += __shfl_xor(s2, 1, 16);
      s2 += __shfl_xor(s2, 2, 16);
      s2 += __shfl_xor(s2, 4, 16);
      s2 += __shfl_xor(s2, 8, 16);
      if (lrow == 0) atomicAdd(&qnf[wr * 64 + i * 16 + lquad * 4 + r], s2);
    }
  }
  __syncthreads();

  // ---- epilogue C: S = zs(128x128) @ proto_slice(64x128)^T; wave -> 32 rows.
  //      proto B-frags straight from global (proto_bf is 64KB, L2-hot). ----
  floatx4 acc2[2][4];
#pragma unroll
  for (int i = 0; i < 2; i++)
#pragma unroll
    for (int j = 0; j < 4; j++) acc2[i][j] = (floatx4){0.f, 0.f, 0.f, 0.f};

#pragma unroll
  for (int ks = 0; ks < 4; ks++) {
    short8 af2[2], bp[4];
#pragma unroll
    for (int i = 0; i < 2; i++)
      af2[i] = *(const short8*)&zs[(wave * 32 + i * 16 + lrow) * ZS_LD + ks * 32 + lquad * 8];
#pragma unroll
    for (int j = 0; j < 4; j++)
      bp[j] = *(const short8*)&proto_bf[(size_t)(j * 16 + lrow) * D_DIM + n0 + ks * 32 + lquad * 8];
#pragma unroll
    for (int i = 0; i < 2; i++)
#pragma unroll
      for (int j = 0; j < 4; j++)
        acc2[i][j] = __builtin_amdgcn_mfma_f32_16x16x32_bf16(af2[i], bp[j], acc2[i][j], 0, 0, 0);
  }

  // ---- epilogue D: out += 2S - qn_slice - pn_slice ----
  size_t qbase = (size_t)mt * 128;
#pragma unroll
  for (int i = 0; i < 2; i++) {
#pragma unroll
    for (int j = 0; j < 4; j++) {
      int c = j * 16 + lrow;
      float pn = pnl[c];
#pragma unroll
      for (int r = 0; r < 4; r++) {
        int ql = wave * 32 + i * 16 + lquad * 4 + r;
        float val = 2.f * acc2[i][j][r] - qnf[ql] - pn;
        atomicAdd(&out[(qbase + ql) * NWAY + c], val);
      }
    }
  }
}

extern "C" void kernel_launch(void* const* d_in, const int* in_sizes, int n_in,
                              void* d_out, int out_size, void* d_ws, size_t ws_size,
                              hipStream_t stream) {
  const float* xs = (const float*)d_in[0];
  const int* ys = (const int*)d_in[1];
  const float* xq = (const float*)d_in[2];
  const float* W = (const float*)d_in[3];
  const float* b = (const float*)d_in[4];
  float* out = (float*)d_out;
  char* ws = (char*)d_ws;

  size_t off = 0;
  auto take = [&](size_t bytes) -> char* {
    char* r = ws + off;
    off += (bytes + 255) & ~(size_t)255;
    return r;
  };
  unsigned short* Wt = (unsigned short*)take((size_t)D_DIM * F_DIM * 2);       // 2 MB
  float* csum = (float*)take((size_t)NWAY * F_DIM * 4);                        // 512 KB
  unsigned short* proto_bf = (unsigned short*)take((size_t)NWAY * D_DIM * 2);  // 64 KB
  float* counts = (float*)take(NWAY * 4);
  float* pnorm_part = (float*)take(4 * NWAY * 4);
  int* order = (int*)take(S_ROWS * 4);
  int* starts = (int*)take((NWAY + 1) * 4);

  // Workspace guard: fail cleanly rather than corrupt device memory.
  if (off > ws_size) return;

  k_prep<<<257, 256, 0, stream>>>(W, Wt, out, pnorm_part, ys, order, starts, counts);
  k1_csum<<<128, 256, 0, stream>>>(xs, order, starts, csum);
  k2_full<<<64, 256, 0, stream>>>(W, csum, b, counts, proto_bf, pnorm_part);
  k3_fused<<<512, 256, 0, stream>>>(xq, Wt, b, proto_bf, pnorm_part, out);
}